// Round 6
// baseline (693.485 us; speedup 1.0000x reference)
//
#include <hip/hip_runtime.h>
#include <hip/hip_bf16.h>
#include <stdint.h>

// Problem constants: B=4, T=2048, C=1024, E=8, H=2048, K=2
#define NB 4
#define NTT 2048
#define NC 1024
#define NE 8
#define NH 2048
#define NKK 2
#define NTOK (NB * NTT)            // 8192
#define CAP (2 * NTOK * NKK / NE)  // 4096

typedef __hip_bfloat16 bf16;
typedef __attribute__((ext_vector_type(8))) short short8;
typedef __attribute__((ext_vector_type(4))) float floatx4;

static __device__ __forceinline__ unsigned short f2b(float f) {
  bf16 h = __float2bfloat16(f);
  unsigned short u;
  __builtin_memcpy(&u, &h, 2);
  return u;
}
static __device__ __forceinline__ int iclamp(int v, int lo, int hi) {
  return v < lo ? lo : (v > hi ? hi : v);
}

// Load 8 consecutive f32 (16B-aligned) and convert to 8 bf16 (RNE).
static __device__ __forceinline__ short8 cvt8(const float* p) {
  const floatx4 a = *reinterpret_cast<const floatx4*>(p);
  const floatx4 b = *reinterpret_cast<const floatx4*>(p + 4);
  short8 r;
  r[0] = (short)f2b(a[0]); r[1] = (short)f2b(a[1]);
  r[2] = (short)f2b(a[2]); r[3] = (short)f2b(a[3]);
  r[4] = (short)f2b(b[0]); r[5] = (short)f2b(b[1]);
  r[6] = (short)f2b(b[2]); r[7] = (short)f2b(b[3]);
  return r;
}

__global__ __launch_bounds__(256) void zero_out_kernel(float* __restrict__ out) {
  const size_t i = ((size_t)blockIdx.x * 256 + threadIdx.x) * 4;
  floatx4 z = {0.f, 0.f, 0.f, 0.f};
  *reinterpret_cast<floatx4*>(out + i) = z;
}

__global__ void zero_cnt_kernel(int* __restrict__ cnt) {
  if (threadIdx.x < NE) cnt[threadIdx.x] = 0;
}

// One wave per token: f32 router scores -> softmax -> top-2 -> slot assign.
// All-f32 so top-2 selection matches the np reference exactly.
__global__ __launch_bounds__(64) void router_kernel(
    const float* __restrict__ x, const float* __restrict__ rw,
    float* __restrict__ rw_out, int* __restrict__ cnt, int* __restrict__ tok,
    float* __restrict__ wslot) {
  const int t = blockIdx.x;
  const int lane = threadIdx.x;
  const float* xr = x + (size_t)t * NC;

  float acc[NE];
#pragma unroll
  for (int e = 0; e < NE; ++e) acc[e] = 0.f;

  for (int i = 0; i < NC / 64; ++i) {
    const int c = i * 64 + lane;
    const float xv = xr[c];
#pragma unroll
    for (int e = 0; e < NE; ++e) acc[e] = fmaf(xv, rw[e * NC + c], acc[e]);
  }
#pragma unroll
  for (int e = 0; e < NE; ++e) {
#pragma unroll
    for (int off = 32; off; off >>= 1) acc[e] += __shfl_xor(acc[e], off, 64);
  }

  // softmax over 8 (fp32)
  float m = acc[0];
#pragma unroll
  for (int e = 1; e < NE; ++e) m = fmaxf(m, acc[e]);
  float p[NE];
  float s = 0.f;
#pragma unroll
  for (int e = 0; e < NE; ++e) {
    p[e] = __expf(acc[e] - m);
    s += p[e];
  }
  const float inv = 1.f / s;
#pragma unroll
  for (int e = 0; e < NE; ++e) p[e] *= inv;

  if (lane < NE) rw_out[(size_t)t * NE + lane] = p[lane];

  if (lane == 0) {
    // top-2, ties -> lower index first (matches jax top_k)
    int i0 = 0;
    float v0 = p[0];
    int i1 = -1;
    float v1 = -1.f;
#pragma unroll
    for (int e = 1; e < NE; ++e) {
      if (p[e] > v0) {
        v1 = v0; i1 = i0;
        v0 = p[e]; i0 = e;
      } else if (p[e] > v1) {
        v1 = p[e]; i1 = e;
      }
    }
    i0 = iclamp(i0, 0, NE - 1);
    i1 = iclamp(i1, 0, NE - 1);
    const float denom = v0 + v1 + 1e-10f;
    const float w0 = v0 / denom, w1 = v1 / denom;

    const int p0 = atomicAdd(&cnt[i0], 1);
    if (p0 < CAP) {
      tok[i0 * CAP + p0] = t;
      wslot[i0 * CAP + p0] = w0;
    }
    const int p1 = atomicAdd(&cnt[i1], 1);
    if (p1 < CAP) {
      tok[i1 * CAP + p1] = t;
      wslot[i1 * CAP + p1] = w1;
    }
  }
}

// Grouped GEMM over one M-chunk per expert. bf16 MFMA 16x16x32, 128x128 tile,
// BK=64, 4 waves (2x2 of 64x64). Staging: global->VGPR (f32 converted to bf16
// on the fly where needed), then ds_write_b128 with XOR chunk swizzle.
// FC=1: A = x (f32, gathered via tok), relu^2 epilogue -> hidden chunk (bf16).
// FC=0: A = hidden chunk (bf16), epilogue f32 atomicAdd of w*val into out.
template <bool FC>
__global__ __launch_bounds__(256) void gemm_moe(
    const float* __restrict__ Ax, const bf16* __restrict__ Ah,
    const float* __restrict__ Bw, bf16* __restrict__ Oh,
    float* __restrict__ Oo, const int* __restrict__ cnt,
    const int* __restrict__ tok, const float* __restrict__ wslot, int ebase,
    int rowOffset, int mch) {
  constexpr int Kd = FC ? NC : NH;
  constexpr int Nd = FC ? NH : NC;
  const int zslot = blockIdx.z;
  const int e = ebase + zslot;
  const int Me = iclamp(cnt[e], 0, CAP);
  const int rowBase = rowOffset + blockIdx.y * 128;  // expert-local row
  if (rowBase >= Me) return;
  const int colBase = blockIdx.x * 128;

  const float* __restrict__ Be = Bw + (size_t)e * Nd * Kd;
  const bf16* __restrict__ Ahc = Ah + (size_t)zslot * mch * NH;

  __shared__ bf16 As[128 * 64];
  __shared__ bf16 Bs[128 * 64];

  const int tid = threadIdx.x;
  const int lane = tid & 63;
  const int wid = tid >> 6;
  const int wm = wid & 1;
  const int wn = wid >> 1;
  const int ml = lane & 15;
  const int quad = lane >> 4;

  // Staging: slot sidx holds (row r = sidx>>3, phys chunk pc = sidx&7);
  // the data placed there is logical chunk lc = pc ^ (r&7).
  const float* gaf[4];
  const bf16* gah[4];
  const float* gbf[4];
  bf16* la[4];
  bf16* lb[4];
#pragma unroll
  for (int it = 0; it < 4; ++it) {
    const int sidx = it * 256 + tid;
    const int r = sidx >> 3;
    const int pc = sidx & 7;
    const int lc = pc ^ (r & 7);
    if (FC) {
      const int grow = rowBase + r;
      const int tk = (grow < Me) ? tok[e * CAP + grow] : 0;
      const int arow = iclamp(tk, 0, NTOK - 1);  // global token row in x
      gaf[it] = Ax + (size_t)arow * NC + lc * 8;
    } else {
      int grow = rowBase + r;
      if (grow > Me - 1) grow = Me - 1;  // stay inside this expert's rows
      const int arow = iclamp(grow - rowOffset, 0, mch - 1);  // chunk-local
      gah[it] = Ahc + (size_t)arow * NH + lc * 8;
    }
    gbf[it] = Be + (size_t)(colBase + r) * Kd + lc * 8;
    la[it] = As + sidx * 8;
    lb[it] = Bs + sidx * 8;
  }

  floatx4 acc[4][4];
#pragma unroll
  for (int mt = 0; mt < 4; ++mt)
#pragma unroll
    for (int nt = 0; nt < 4; ++nt) acc[mt][nt] = floatx4{0.f, 0.f, 0.f, 0.f};

  // Fragment LDS element offsets (per lane): row = ..+ml, chunk q = kk*4+quad
  int aoff[4][2], boff[4][2];
#pragma unroll
  for (int t4 = 0; t4 < 4; ++t4)
#pragma unroll
    for (int kk = 0; kk < 2; ++kk) {
      const int ra = wm * 64 + t4 * 16 + ml;
      const int rb = wn * 64 + t4 * 16 + ml;
      const int q = kk * 4 + quad;
      aoff[t4][kk] = (ra * 8 + (q ^ (ra & 7))) * 8;
      boff[t4][kk] = (rb * 8 + (q ^ (rb & 7))) * 8;
    }

  const int nkb = Kd >> 6;
  for (int kb = 0; kb < nkb; ++kb) {
    const int k0 = kb << 6;
    short8 sa[4], sb[4];
#pragma unroll
    for (int it = 0; it < 4; ++it) {
      if (FC)
        sa[it] = cvt8(gaf[it] + k0);
      else
        sa[it] = *reinterpret_cast<const short8*>(gah[it] + k0);
      sb[it] = cvt8(gbf[it] + k0);
    }
    __syncthreads();  // previous iteration's ds_reads done before overwrite
#pragma unroll
    for (int it = 0; it < 4; ++it) {
      *reinterpret_cast<short8*>(la[it]) = sa[it];
      *reinterpret_cast<short8*>(lb[it]) = sb[it];
    }
    __syncthreads();  // tile visible to all waves

    short8 af[4][2], bff[4][2];
#pragma unroll
    for (int mt = 0; mt < 4; ++mt)
#pragma unroll
      for (int kk = 0; kk < 2; ++kk)
        af[mt][kk] = *reinterpret_cast<const short8*>(&As[aoff[mt][kk]]);
#pragma unroll
    for (int nt = 0; nt < 4; ++nt)
#pragma unroll
      for (int kk = 0; kk < 2; ++kk)
        bff[nt][kk] = *reinterpret_cast<const short8*>(&Bs[boff[nt][kk]]);
#pragma unroll
    for (int kk = 0; kk < 2; ++kk)
#pragma unroll
      for (int mt = 0; mt < 4; ++mt)
#pragma unroll
        for (int nt = 0; nt < 4; ++nt)
          acc[mt][nt] = __builtin_amdgcn_mfma_f32_16x16x32_bf16(
              af[mt][kk], bff[nt][kk], acc[mt][nt], 0, 0, 0);
  }

  // Epilogue: C/D layout col=lane&15, row=quad*4+reg (m89/m91 verified).
  if (FC) {
    bf16* __restrict__ O = Oh + (size_t)zslot * mch * NH;
    const int rlBase = rowBase - rowOffset;  // chunk-local
#pragma unroll
    for (int mt = 0; mt < 4; ++mt) {
      const int rl = wm * 64 + mt * 16 + quad * 4;
#pragma unroll
      for (int nt = 0; nt < 4; ++nt) {
        const int cc = colBase + wn * 64 + nt * 16 + ml;
        const floatx4 v = acc[mt][nt];
#pragma unroll
        for (int rg = 0; rg < 4; ++rg) {
          if (rowBase + rl + rg < Me) {
            float f = fmaxf(v[rg], 0.f);
            f = f * f;  // relu^2
            O[(size_t)(rlBase + rl + rg) * NH + cc] = __float2bfloat16(f);
          }
        }
      }
    }
  } else {
#pragma unroll
    for (int mt = 0; mt < 4; ++mt) {
      const int rl = wm * 64 + mt * 16 + quad * 4;
#pragma unroll
      for (int rg = 0; rg < 4; ++rg) {
        const int re = rowBase + rl + rg;  // expert-local row
        if (re < Me) {
          const int t = iclamp(tok[e * CAP + re], 0, NTOK - 1);
          const float w = wslot[e * CAP + re];
#pragma unroll
          for (int nt = 0; nt < 4; ++nt) {
            const int cc = colBase + wn * 64 + nt * 16 + ml;
            atomicAdd(Oo + (size_t)t * NC + cc, w * acc[mt][nt][rg]);
          }
        }
      }
    }
  }
}

extern "C" void kernel_launch(void* const* d_in, const int* in_sizes, int n_in,
                              void* d_out, int out_size, void* d_ws,
                              size_t ws_size, hipStream_t stream) {
  const float* x = (const float*)d_in[0];      // [8192, 1024] f32
  const float* rw = (const float*)d_in[1];     // [8, 1024] f32
  const float* fcw = (const float*)d_in[2];    // [8, 2048, 1024] f32
  const float* pjw = (const float*)d_in[3];    // [8, 1024, 2048] f32
  float* out = (float*)d_out;                  // [8192,1024] ++ [8192,8] f32
  float* rw_out = out + (size_t)NTOK * NC;

  // Workspace: 262.4 KB bookkeeping + adaptive bf16 hidden chunk.
  char* ws = (char*)d_ws;
  int* cnt = (int*)ws;                           // 256 B
  int* tok = (int*)(ws + 256);                   // 128 KB
  float* wslot = (float*)(ws + 256 + 131072);    // 128 KB
  bf16* hidden = (bf16*)(ws + 262400);           // nexp * mch * NH bf16
  (void)in_sizes; (void)n_in; (void)out_size;

  // Tier A: all experts per launch, largest chunk that fits (4.5..134 MB).
  // Tier B: one expert at a time, 128-row chunks (total need 0.77 MB).
  int nexp = 1, mch = 128;
  for (int cand = CAP; cand >= 128; cand >>= 1) {
    const size_t need = 262400 + (size_t)NE * cand * NH * 2;
    if (need <= ws_size) { nexp = NE; mch = cand; break; }
  }

  zero_out_kernel<<<NTOK * NC / 1024, 256, 0, stream>>>(out);
  zero_cnt_kernel<<<1, 64, 0, stream>>>(cnt);
  router_kernel<<<NTOK, 64, 0, stream>>>(x, rw, rw_out, cnt, tok, wslot);

  for (int eb = 0; eb < NE; eb += nexp) {
    for (int c = 0; c < CAP / mch; ++c) {
      // fc: N=H=2048, K=C=1024, gather from x (f32->bf16), relu^2 -> hidden
      gemm_moe<true><<<dim3(NH / 128, mch / 128, nexp), 256, 0, stream>>>(
          x, hidden, fcw, hidden, out, cnt, tok, wslot, eb, c * mch, mch);
      // proj: N=C=1024, K=H=2048, combine w*val into out via f32 atomics
      gemm_moe<false><<<dim3(NC / 128, mch / 128, nexp), 256, 0, stream>>>(
          x, hidden, pjw, hidden, out, cnt, tok, wslot, eb, c * mch, mch);
    }
  }
}

// Round 7
// 627.888 us; speedup vs baseline: 1.1045x; 1.1045x over previous
//
#include <hip/hip_runtime.h>
#include <hip/hip_bf16.h>
#include <stdint.h>

// Problem constants: B=4, T=2048, C=1024, E=8, H=2048, K=2
#define NB 4
#define NTT 2048
#define NC 1024
#define NE 8
#define NH 2048
#define NKK 2
#define NTOK (NB * NTT)            // 8192
#define CAP (2 * NTOK * NKK / NE)  // 4096

typedef __hip_bfloat16 bf16;
typedef __attribute__((ext_vector_type(8))) short short8;
typedef __attribute__((ext_vector_type(4))) short short4v;
typedef __attribute__((ext_vector_type(4))) float floatx4;

typedef const __attribute__((address_space(1))) void* gas_ptr;
typedef __attribute__((address_space(3))) void* las_ptr;

static __device__ __forceinline__ void async_copy16(const void* g, void* l) {
  // 16B/lane; LDS dest = wave-uniform base + lane*16 (m97/m104 semantics).
  // Our la[] addresses are exactly lane-contiguous in that order.
  __builtin_amdgcn_global_load_lds((gas_ptr)g, (las_ptr)l, 16, 0, 0);
}

static __device__ __forceinline__ unsigned short f2b(float f) {
  bf16 h = __float2bfloat16(f);
  unsigned short u;
  __builtin_memcpy(&u, &h, 2);
  return u;
}
static __device__ __forceinline__ int iclamp(int v, int lo, int hi) {
  return v < lo ? lo : (v > hi ? hi : v);
}

__global__ __launch_bounds__(256) void zero_out_kernel(float* __restrict__ out) {
  const size_t i = ((size_t)blockIdx.x * 256 + threadIdx.x) * 4;
  floatx4 z = {0.f, 0.f, 0.f, 0.f};
  *reinterpret_cast<floatx4*>(out + i) = z;
}

__global__ void zero_cnt_kernel(int* __restrict__ cnt) {
  if (threadIdx.x < NE) cnt[threadIdx.x] = 0;
}

// f32 -> bf16 (RNE), 8 elements/thread. n must be divisible by grid*256*8.
__global__ __launch_bounds__(256) void cvt_kernel(const float* __restrict__ src,
                                                  bf16* __restrict__ dst) {
  const size_t i = ((size_t)blockIdx.x * 256 + threadIdx.x) * 8;
  const floatx4 a = *reinterpret_cast<const floatx4*>(src + i);
  const floatx4 b = *reinterpret_cast<const floatx4*>(src + i + 4);
  short8 r;
  r[0] = (short)f2b(a[0]); r[1] = (short)f2b(a[1]);
  r[2] = (short)f2b(a[2]); r[3] = (short)f2b(a[3]);
  r[4] = (short)f2b(b[0]); r[5] = (short)f2b(b[1]);
  r[6] = (short)f2b(b[2]); r[7] = (short)f2b(b[3]);
  *reinterpret_cast<short8*>(dst + i) = r;
}

// One wave per token: f32 router (float4-vectorized) -> softmax -> top-2 ->
// slot assignment. Also emits x_bf16 (free conversion: x is read anyway).
__global__ __launch_bounds__(64) void router_kernel(
    const float* __restrict__ x, const float* __restrict__ rw,
    float* __restrict__ rw_out, int* __restrict__ cnt, int* __restrict__ tok,
    float* __restrict__ wslot, bf16* __restrict__ xb) {
  const int t = blockIdx.x;
  const int lane = threadIdx.x;
  const floatx4* xr4 = reinterpret_cast<const floatx4*>(x + (size_t)t * NC);
  const floatx4* rw4 = reinterpret_cast<const floatx4*>(rw);
  bf16* xbr = xb + (size_t)t * NC;

  float acc[NE];
#pragma unroll
  for (int e = 0; e < NE; ++e) acc[e] = 0.f;

#pragma unroll
  for (int i = 0; i < 4; ++i) {
    const int idx = i * 64 + lane;  // float4 index within the row (0..255)
    const floatx4 xv = xr4[idx];
    short4v o;
    o[0] = (short)f2b(xv[0]); o[1] = (short)f2b(xv[1]);
    o[2] = (short)f2b(xv[2]); o[3] = (short)f2b(xv[3]);
    *reinterpret_cast<short4v*>(xbr + idx * 4) = o;
#pragma unroll
    for (int e = 0; e < NE; ++e) {
      const floatx4 wv = rw4[e * 256 + idx];
      acc[e] = fmaf(xv[0], wv[0], acc[e]);
      acc[e] = fmaf(xv[1], wv[1], acc[e]);
      acc[e] = fmaf(xv[2], wv[2], acc[e]);
      acc[e] = fmaf(xv[3], wv[3], acc[e]);
    }
  }
#pragma unroll
  for (int e = 0; e < NE; ++e) {
#pragma unroll
    for (int off = 32; off; off >>= 1) acc[e] += __shfl_xor(acc[e], off, 64);
  }

  // softmax over 8 (fp32)
  float m = acc[0];
#pragma unroll
  for (int e = 1; e < NE; ++e) m = fmaxf(m, acc[e]);
  float p[NE];
  float s = 0.f;
#pragma unroll
  for (int e = 0; e < NE; ++e) {
    p[e] = __expf(acc[e] - m);
    s += p[e];
  }
  const float inv = 1.f / s;
#pragma unroll
  for (int e = 0; e < NE; ++e) p[e] *= inv;

  if (lane < NE) rw_out[(size_t)t * NE + lane] = p[lane];

  if (lane == 0) {
    // top-2, ties -> lower index first (matches jax top_k)
    int i0 = 0;
    float v0 = p[0];
    int i1 = -1;
    float v1 = -1.f;
#pragma unroll
    for (int e = 1; e < NE; ++e) {
      if (p[e] > v0) {
        v1 = v0; i1 = i0;
        v0 = p[e]; i0 = e;
      } else if (p[e] > v1) {
        v1 = p[e]; i1 = e;
      }
    }
    i0 = iclamp(i0, 0, NE - 1);  // insurance (see round-5 post-mortem)
    i1 = iclamp(i1, 0, NE - 1);
    const float denom = v0 + v1 + 1e-10f;
    const float w0 = v0 / denom, w1 = v1 / denom;

    const int p0 = atomicAdd(&cnt[i0], 1);
    if (p0 < CAP) {
      tok[i0 * CAP + p0] = t;
      wslot[i0 * CAP + p0] = w0;
    }
    const int p1 = atomicAdd(&cnt[i1], 1);
    if (p1 < CAP) {
      tok[i1 * CAP + p1] = t;
      wslot[i1 * CAP + p1] = w1;
    }
  }
}

// Grouped GEMM over one M-chunk per expert. All-bf16 inputs. MFMA 16x16x32,
// 128x128 tile, BK=64, 4 waves (2x2 of 64x64), global_load_lds width-16
// staging (m97), XOR chunk swizzle applied on the GLOBAL source side.
// FC=1: A = x_bf16 gathered via tok, relu^2 epilogue -> hidden chunk (bf16).
// FC=0: A = hidden chunk (bf16), epilogue f32 atomicAdd of w*val into out.
template <bool FC>
__global__ __launch_bounds__(256) void gemm_moe(
    const bf16* __restrict__ Axb, const bf16* __restrict__ Ah,
    const bf16* __restrict__ Bw, bf16* __restrict__ Oh,
    float* __restrict__ Oo, const int* __restrict__ cnt,
    const int* __restrict__ tok, const float* __restrict__ wslot,
    int rowOffset, int mch) {
  constexpr int Kd = FC ? NC : NH;
  constexpr int Nd = FC ? NH : NC;
  const int e = blockIdx.z;
  const int Me = iclamp(cnt[e], 0, CAP);
  const int rowBase = rowOffset + blockIdx.y * 128;  // expert-local row
  if (rowBase >= Me) return;
  const int colBase = blockIdx.x * 128;

  const bf16* __restrict__ Be = Bw + (size_t)e * Nd * Kd;
  const bf16* __restrict__ Ahc = Ah + (size_t)e * mch * NH;

  __shared__ bf16 As[128 * 64];
  __shared__ bf16 Bs[128 * 64];

  const int tid = threadIdx.x;
  const int lane = tid & 63;
  const int wid = tid >> 6;
  const int wm = wid & 1;
  const int wn = wid >> 1;
  const int ml = lane & 15;
  const int quad = lane >> 4;

  // Staging: slot sidx holds (row r = sidx>>3, phys chunk pc = sidx&7);
  // data placed there is logical chunk lc = pc ^ (r&7).
  const bf16* ga[4];
  const bf16* gb[4];
  bf16* la[4];
  bf16* lb[4];
#pragma unroll
  for (int it = 0; it < 4; ++it) {
    const int sidx = it * 256 + tid;
    const int r = sidx >> 3;
    const int pc = sidx & 7;
    const int lc = pc ^ (r & 7);
    if (FC) {
      const int grow = rowBase + r;
      const int tk = (grow < Me) ? tok[e * CAP + grow] : 0;
      const int arow = iclamp(tk, 0, NTOK - 1);  // global token row in x_bf16
      ga[it] = Axb + (size_t)arow * NC + lc * 8;
    } else {
      int grow = rowBase + r;
      if (grow > Me - 1) grow = Me - 1;  // stay inside this expert's rows
      const int arow = iclamp(grow - rowOffset, 0, mch - 1);  // chunk-local
      ga[it] = Ahc + (size_t)arow * NH + lc * 8;
    }
    gb[it] = Be + (size_t)(colBase + r) * Kd + lc * 8;
    la[it] = As + sidx * 8;
    lb[it] = Bs + sidx * 8;
  }

  floatx4 acc[4][4];
#pragma unroll
  for (int mt = 0; mt < 4; ++mt)
#pragma unroll
    for (int nt = 0; nt < 4; ++nt) acc[mt][nt] = floatx4{0.f, 0.f, 0.f, 0.f};

  // Fragment LDS element offsets (per lane): row = ..+ml, chunk q = kk*4+quad
  int aoff[4][2], boff[4][2];
#pragma unroll
  for (int t4 = 0; t4 < 4; ++t4)
#pragma unroll
    for (int kk = 0; kk < 2; ++kk) {
      const int ra = wm * 64 + t4 * 16 + ml;
      const int rb = wn * 64 + t4 * 16 + ml;
      const int q = kk * 4 + quad;
      aoff[t4][kk] = (ra * 8 + (q ^ (ra & 7))) * 8;
      boff[t4][kk] = (rb * 8 + (q ^ (rb & 7))) * 8;
    }

  // Prologue: stage tile k0=0
#pragma unroll
  for (int it = 0; it < 4; ++it) async_copy16(ga[it], la[it]);
#pragma unroll
  for (int it = 0; it < 4; ++it) async_copy16(gb[it], lb[it]);

  const int nkb = Kd >> 6;
  for (int kb = 0; kb < nkb; ++kb) {
    __syncthreads();  // drains vmcnt -> LDS tile ready
    short8 af[4][2], bff[4][2];
#pragma unroll
    for (int mt = 0; mt < 4; ++mt)
#pragma unroll
      for (int kk = 0; kk < 2; ++kk)
        af[mt][kk] = *reinterpret_cast<const short8*>(&As[aoff[mt][kk]]);
#pragma unroll
    for (int nt = 0; nt < 4; ++nt)
#pragma unroll
      for (int kk = 0; kk < 2; ++kk)
        bff[nt][kk] = *reinterpret_cast<const short8*>(&Bs[boff[nt][kk]]);
#pragma unroll
    for (int kk = 0; kk < 2; ++kk)
#pragma unroll
      for (int mt = 0; mt < 4; ++mt)
#pragma unroll
        for (int nt = 0; nt < 4; ++nt)
          acc[mt][nt] = __builtin_amdgcn_mfma_f32_16x16x32_bf16(
              af[mt][kk], bff[nt][kk], acc[mt][nt], 0, 0, 0);
    __syncthreads();  // all ds_reads done before restage
    if (kb + 1 < nkb) {
      const int k0 = (kb + 1) << 6;
#pragma unroll
      for (int it = 0; it < 4; ++it) async_copy16(ga[it] + k0, la[it]);
#pragma unroll
      for (int it = 0; it < 4; ++it) async_copy16(gb[it] + k0, lb[it]);
    }
  }

  // Epilogue: C/D layout col=lane&15, row=quad*4+reg (m89/m91 verified).
  if (FC) {
    bf16* __restrict__ O = Oh + (size_t)e * mch * NH;
    const int rlBase = rowBase - rowOffset;  // chunk-local
#pragma unroll
    for (int mt = 0; mt < 4; ++mt) {
      const int rl = wm * 64 + mt * 16 + quad * 4;
#pragma unroll
      for (int nt = 0; nt < 4; ++nt) {
        const int cc = colBase + wn * 64 + nt * 16 + ml;
        const floatx4 v = acc[mt][nt];
#pragma unroll
        for (int rg = 0; rg < 4; ++rg) {
          if (rowBase + rl + rg < Me) {
            float f = fmaxf(v[rg], 0.f);
            f = f * f;  // relu^2
            O[(size_t)(rlBase + rl + rg) * NH + cc] = __float2bfloat16(f);
          }
        }
      }
    }
  } else {
#pragma unroll
    for (int mt = 0; mt < 4; ++mt) {
      const int rl = wm * 64 + mt * 16 + quad * 4;
#pragma unroll
      for (int rg = 0; rg < 4; ++rg) {
        const int re = rowBase + rl + rg;  // expert-local row
        if (re < Me) {
          const int t = iclamp(tok[e * CAP + re], 0, NTOK - 1);
          const float w = wslot[e * CAP + re];
#pragma unroll
          for (int nt = 0; nt < 4; ++nt) {
            const int cc = colBase + wn * 64 + nt * 16 + ml;
            atomicAdd(Oo + (size_t)t * NC + cc, w * acc[mt][nt][rg]);
          }
        }
      }
    }
  }
}

extern "C" void kernel_launch(void* const* d_in, const int* in_sizes, int n_in,
                              void* d_out, int out_size, void* d_ws,
                              size_t ws_size, hipStream_t stream) {
  const float* x = (const float*)d_in[0];      // [8192, 1024] f32
  const float* rw = (const float*)d_in[1];     // [8, 1024] f32
  const float* fcw = (const float*)d_in[2];    // [8, 2048, 1024] f32
  const float* pjw = (const float*)d_in[3];    // [8, 1024, 2048] f32
  float* out = (float*)d_out;                  // [8192,1024] ++ [8192,8] f32
  float* rw_out = out + (size_t)NTOK * NC;

  // Workspace (ws_size >= 134.5 MB proven in round 6 by Tier-A dispatch count):
  // bookkeeping 262.4 KB + x_bf16 16.8 MB + fcw_bf16 33.6 MB + pjw_bf16
  // 33.6 MB = 84.2 MB fixed, + bf16 hidden chunk (mch ladder).
  char* ws = (char*)d_ws;
  int* cnt = (int*)ws;                            // 256 B
  int* tok = (int*)(ws + 256);                    // 128 KB
  float* wslot = (float*)(ws + 256 + 131072);     // 128 KB
  bf16* xb = (bf16*)(ws + 262400);                // 16.78 MB
  bf16* fcwb = (bf16*)(ws + 262400 + 16777216);   // 33.55 MB
  bf16* pjwb = (bf16*)(ws + 262400 + 16777216 + 33554432);
  const size_t fixed = 262400 + 16777216 + 2 * 33554432;  // 84.15 MB
  bf16* hidden = (bf16*)(ws + fixed);             // NE * mch * NH bf16
  (void)in_sizes; (void)n_in; (void)out_size;

  int mch = 128;
  for (int cand = CAP; cand >= 128; cand >>= 1) {
    const size_t need = fixed + (size_t)NE * cand * NH * 2;
    if (need <= ws_size) { mch = cand; break; }
  }

  zero_out_kernel<<<NTOK * NC / 1024, 256, 0, stream>>>(out);
  zero_cnt_kernel<<<1, 64, 0, stream>>>(cnt);
  cvt_kernel<<<NE * NH * NC / 2048, 256, 0, stream>>>(fcw, fcwb);
  cvt_kernel<<<NE * NC * NH / 2048, 256, 0, stream>>>(pjw, pjwb);
  router_kernel<<<NTOK, 64, 0, stream>>>(x, rw, rw_out, cnt, tok, wslot, xb);

  for (int c = 0; c < CAP / mch; ++c) {
    // fc: N=H=2048, K=C=1024, gather bf16 x, relu^2 -> hidden chunk
    gemm_moe<true><<<dim3(NH / 128, mch / 128, NE), 256, 0, stream>>>(
        xb, hidden, fcwb, hidden, out, cnt, tok, wslot, c * mch, mch);
    // proj: N=C=1024, K=H=2048, combine w*val into out via f32 atomics
    gemm_moe<false><<<dim3(NC / 128, mch / 128, NE), 256, 0, stream>>>(
        xb, hidden, pjwb, hidden, out, cnt, tok, wslot, c * mch, mch);
  }
}